// Round 9
// baseline (543.249 us; speedup 1.0000x reference)
//
#include <hip/hip_runtime.h>

#define B_TOK 32768
#define D_IN  256
#define H_LAT 8192
#define TOPK  32
#define MT    64          // rows per block
#define NT    128         // h-cols per chunk
#define NCH   (H_LAT / NT)
#define CAP   144         // candidate pool per row (thr=2.3sigma -> lambda~90)
#define DELTA 0.016f      // exact-rescore window; ~8 sigma of bf16-GEMM+pack err

typedef __attribute__((ext_vector_type(4))) float f32x4;
typedef __attribute__((ext_vector_type(8))) short bf16x8;

__device__ __forceinline__ unsigned short f2bf(float f) {   // RNE fp32->bf16
    unsigned u = __float_as_uint(f);
    return (unsigned short)((u + 0x7fffu + ((u >> 16) & 1u)) >> 16);
}
__device__ __forceinline__ float bf2f(unsigned short u) {
    return __uint_as_float((unsigned)u << 16);
}

// Kernel A: W_enc fp32 -> bf16 SWIZZLED to MFMA-fragment order (+ sum W^2);
// W_dec fp32 -> bf16 linear (decoder copy).
__global__ __launch_bounds__(256)
void conv_kernel(const float* __restrict__ W, unsigned short* __restrict__ Wbf,
                 float* __restrict__ s2w, const float* __restrict__ Wd,
                 unsigned short* __restrict__ Wdbf) {
    const int total4 = (H_LAT * D_IN) / 4;
    float acc = 0.0f;
    for (int j = blockIdx.x * blockDim.x + threadIdx.x; j < total4;
         j += gridDim.x * blockDim.x) {
        const int e4   = j & 1;                 // which half of the 8-elem frag
        const int lane = (j >> 1) & 63;
        const int c8   = (j >> 7) & 7;
        const int ct16 = j >> 10;               // 16-col tile, 0..511
        const int h = ct16 * 16 + (lane & 15);
        const int k = c8 * 32 + (lane >> 4) * 8 + e4 * 4;
        const float4 v = *(const float4*)(W + (size_t)h * D_IN + k);
        acc += v.x * v.x + v.y * v.y + v.z * v.z + v.w * v.w;
        ushort4 o;
        o.x = f2bf(v.x); o.y = f2bf(v.y); o.z = f2bf(v.z); o.w = f2bf(v.w);
        ((ushort4*)Wbf)[j] = o;                 // coalesced write
    }
    for (int i = blockIdx.x * blockDim.x + threadIdx.x; i < total4;
         i += gridDim.x * blockDim.x) {
        const float4 v = ((const float4*)Wd)[i];
        ushort4 o;
        o.x = f2bf(v.x); o.y = f2bf(v.y); o.z = f2bf(v.z); o.w = f2bf(v.w);
        ((ushort4*)Wdbf)[i] = o;
    }
#pragma unroll
    for (int off = 32; off > 0; off >>= 1) acc += __shfl_down(acc, off, 64);
    if ((threadIdx.x & 63) == 0) atomicAdd(s2w, acc);
}

// Kernel B: GEMM + filter only. R8 structure with 4-CHUNK groups (A read once
// per 4 chunks -> A-LDS traffic halved) and pool dumped coalesced to global
// for the select kernel.
__global__ __launch_bounds__(512, 4)
void sae_main(const float* __restrict__ x, const float* __restrict__ b_enc,
              const float* __restrict__ b_dec,
              const unsigned short* __restrict__ Wbf, const float* __restrict__ s2w,
              unsigned* __restrict__ pool_g, int* __restrict__ cnt_g) {
    // smem: [0, 32768)     A_frag[32][512] ushort
    //       [32768, 69632) pool[64][144]
    __shared__ __align__(16) char smem[32768 + MT * CAP * 4];
    __shared__ int   cnt[MT];
    __shared__ float thr[MT];

    unsigned short* A = (unsigned short*)smem;
    auto pool = reinterpret_cast<unsigned (*)[CAP]>(smem + 32768);

    const int tid  = threadIdx.x;
    const int row0 = blockIdx.x * MT;
    const int wave = tid >> 6, lane = tid & 63;
    const int l15 = lane & 15, quad = lane >> 4;

    if (tid < MT) { cnt[tid] = 0; thr[tid] = 0.0f; }
    __syncthreads();

    // ---- Phase 0: stage (x - b_dec) -> bf16 LDS in FRAGMENT order ----
    {
        const int r = tid >> 3, q = tid & 7;                // 8 threads/row, 32 k each
        const float* xr = x + (size_t)(row0 + r) * D_IN + q * 32;
        const float* bd = b_dec + q * 32;
        unsigned short* dst = A + ((r >> 4) * 8 + q) * 512 + (r & 15) * 8;
        float s2 = 0.0f;
#pragma unroll
        for (int j = 0; j < 4; ++j) {                       // j = quad-of-k
            const float4 a = ((const float4*)xr)[2 * j];
            const float4 b = ((const float4*)xr)[2 * j + 1];
            const float4 da = ((const float4*)bd)[2 * j];
            const float4 db = ((const float4*)bd)[2 * j + 1];
            float v[8] = {a.x - da.x, a.y - da.y, a.z - da.z, a.w - da.w,
                          b.x - db.x, b.y - db.y, b.z - db.z, b.w - db.w};
            ushort4 p0, p1;
            p0.x = f2bf(v[0]); p0.y = f2bf(v[1]); p0.z = f2bf(v[2]); p0.w = f2bf(v[3]);
            p1.x = f2bf(v[4]); p1.y = f2bf(v[5]); p1.z = f2bf(v[6]); p1.w = f2bf(v[7]);
#pragma unroll
            for (int e = 0; e < 8; ++e) s2 += v[e] * v[e];
            *(ushort4*)(dst + j * 128)     = p0;
            *(ushort4*)(dst + j * 128 + 4) = p1;
        }
        atomicAdd(&thr[r], s2);
    }
    __syncthreads();
    if (tid < MT) {
        const float s2wm = s2w[0] * (1.0f / ((float)H_LAT * (float)D_IN));
        thr[tid] = 2.3f * sqrtf(s2wm * thr[tid]);
    }
    __syncthreads();

    float thrv[4][4];
#pragma unroll
    for (int mt = 0; mt < 4; ++mt)
#pragma unroll
        for (int qi = 0; qi < 4; ++qi) thrv[mt][qi] = thr[mt * 16 + quad * 4 + qi];

    // ---- Phase 1: MFMA K-loop over 4-chunk groups; wave owns 16-col strip ----
    const unsigned short* bp = Wbf + (size_t)(wave * 8) * 512 + lane * 8;
    const unsigned short* ap = A + lane * 8;                // conflict-free A base
    const float* bep = b_enc + wave * 16 + l15;
    int col0 = wave * 16 + l15;

    int pos[4][4];
    auto collect = [&](const f32x4 (&ac)[4], int cbase) {
        const unsigned colk = (unsigned)(8191 - cbase);
#pragma unroll
        for (int mt = 0; mt < 4; ++mt)
#pragma unroll
            for (int qi = 0; qi < 4; ++qi) {
                pos[mt][qi] = -1;
                if (ac[mt][qi] > thrv[mt][qi])
                    pos[mt][qi] = atomicAdd(&cnt[mt * 16 + quad * 4 + qi], 1);
            }
#pragma unroll
        for (int mt = 0; mt < 4; ++mt)
#pragma unroll
            for (int qi = 0; qi < 4; ++qi) {
                if ((unsigned)pos[mt][qi] < CAP)
                    pool[mt * 16 + quad * 4 + qi][pos[mt][qi]] =
                        ((unsigned)f2bf(ac[mt][qi]) << 13) | colk;
            }
    };

    for (int g = 0; g < NCH; g += 4) {
        const float bv0 = bep[0],      bv1 = bep[NT];
        const float bv2 = bep[2 * NT], bv3 = bep[3 * NT];

        f32x4 acc0[4], acc1[4], acc2[4], acc3[4];
#pragma unroll
        for (int mt = 0; mt < 4; ++mt) {
            acc0[mt] = {bv0, bv0, bv0, bv0};                // C-in = bias
            acc1[mt] = {bv1, bv1, bv1, bv1};
            acc2[mt] = {bv2, bv2, bv2, bv2};
            acc3[mt] = {bv3, bv3, bv3, bv3};
        }

#pragma unroll
        for (int c8 = 0; c8 < 8; ++c8) {
            const bf16x8 a0 = *(const bf16x8*)(ap + (0 * 8 + c8) * 512);
            const bf16x8 a1 = *(const bf16x8*)(ap + (1 * 8 + c8) * 512);
            const bf16x8 a2 = *(const bf16x8*)(ap + (2 * 8 + c8) * 512);
            const bf16x8 a3 = *(const bf16x8*)(ap + (3 * 8 + c8) * 512);
            const bf16x8 w0 = *(const bf16x8*)(bp + c8 * 512);
            const bf16x8 w1 = *(const bf16x8*)(bp + 32768 + c8 * 512);
            const bf16x8 w2 = *(const bf16x8*)(bp + 65536 + c8 * 512);
            const bf16x8 w3 = *(const bf16x8*)(bp + 98304 + c8 * 512);
            acc0[0] = __builtin_amdgcn_mfma_f32_16x16x32_bf16(a0, w0, acc0[0], 0, 0, 0);
            acc0[1] = __builtin_amdgcn_mfma_f32_16x16x32_bf16(a1, w0, acc0[1], 0, 0, 0);
            acc0[2] = __builtin_amdgcn_mfma_f32_16x16x32_bf16(a2, w0, acc0[2], 0, 0, 0);
            acc0[3] = __builtin_amdgcn_mfma_f32_16x16x32_bf16(a3, w0, acc0[3], 0, 0, 0);
            acc1[0] = __builtin_amdgcn_mfma_f32_16x16x32_bf16(a0, w1, acc1[0], 0, 0, 0);
            acc1[1] = __builtin_amdgcn_mfma_f32_16x16x32_bf16(a1, w1, acc1[1], 0, 0, 0);
            acc1[2] = __builtin_amdgcn_mfma_f32_16x16x32_bf16(a2, w1, acc1[2], 0, 0, 0);
            acc1[3] = __builtin_amdgcn_mfma_f32_16x16x32_bf16(a3, w1, acc1[3], 0, 0, 0);
            acc2[0] = __builtin_amdgcn_mfma_f32_16x16x32_bf16(a0, w2, acc2[0], 0, 0, 0);
            acc2[1] = __builtin_amdgcn_mfma_f32_16x16x32_bf16(a1, w2, acc2[1], 0, 0, 0);
            acc2[2] = __builtin_amdgcn_mfma_f32_16x16x32_bf16(a2, w2, acc2[2], 0, 0, 0);
            acc2[3] = __builtin_amdgcn_mfma_f32_16x16x32_bf16(a3, w2, acc2[3], 0, 0, 0);
            acc3[0] = __builtin_amdgcn_mfma_f32_16x16x32_bf16(a0, w3, acc3[0], 0, 0, 0);
            acc3[1] = __builtin_amdgcn_mfma_f32_16x16x32_bf16(a1, w3, acc3[1], 0, 0, 0);
            acc3[2] = __builtin_amdgcn_mfma_f32_16x16x32_bf16(a2, w3, acc3[2], 0, 0, 0);
            acc3[3] = __builtin_amdgcn_mfma_f32_16x16x32_bf16(a3, w3, acc3[3], 0, 0, 0);
        }

        collect(acc0, col0);
        collect(acc1, col0 + NT);
        collect(acc2, col0 + 2 * NT);
        collect(acc3, col0 + 3 * NT);

        bp  += 4 * 32768;                                   // 4 chunks (8 ct16 each)
        bep += 4 * NT;
        col0 += 4 * NT;
    }
    __syncthreads();    // pools complete

    // ---- Dump pool + counts coalesced to global for the select kernel ----
    {
        unsigned* pg = pool_g + (size_t)row0 * CAP;
        const unsigned* ps = (const unsigned*)pool;
        for (int i = tid; i < MT * CAP; i += 512) pg[i] = ps[i];
        if (tid < MT) cnt_g[row0 + tid] = cnt[tid];
    }
}

// Kernel C: select + decode, ONE WAVE PER ROW (no barriers; wave-lockstep
// ordering replaces __syncthreads). 4096 blocks x 512 thr, tiny LDS ->
// high occupancy for the shuffle/rescore/gather latency chains.
__global__ __launch_bounds__(512, 4)
void sae_select(const float* __restrict__ x, const float* __restrict__ W_enc,
                const float* __restrict__ b_enc, const float* __restrict__ b_dec,
                float* __restrict__ out, const unsigned short* __restrict__ Wdbf,
                const unsigned* __restrict__ pool_g, const int* __restrict__ cnt_g) {
    __shared__ unsigned short ext_i[8][64];
    __shared__ float          ext_v[8][64];

    const int tid = threadIdx.x, wave = tid >> 6, lane = tid & 63;
    const int r = blockIdx.x * 8 + wave;                    // global row
    const unsigned* pr = pool_g + (size_t)r * CAP;
    const int n = min(cnt_g[r], CAP);

    // ---- rank-count on packed keys -> top-64 (idx + approx val) ----
    unsigned p[3]; int rk[3];
    const int S = (n <= 128) ? 2 : 3;                       // wave-uniform
#pragma unroll
    for (int e = 0; e < 3; ++e) {
        const int c = e * 64 + lane;
        p[e] = (c < n) ? pr[c] : (unsigned)(c + 1);         // unique tiny sentinels
        rk[e] = 0;
    }
    if (S == 2) {
        for (int s = 0; s < 64; ++s) {
            const int src = (lane + s) & 63;
            const unsigned q0 = (unsigned)__shfl((int)p[0], src, 64);
            const unsigned q1 = (unsigned)__shfl((int)p[1], src, 64);
            rk[0] += (q0 > p[0]) + (q1 > p[0]);
            rk[1] += (q0 > p[1]) + (q1 > p[1]);
        }
    } else {
        for (int s = 0; s < 64; ++s) {
            const int src = (lane + s) & 63;
#pragma unroll
            for (int e = 0; e < 3; ++e) {
                const unsigned q = (unsigned)__shfl((int)p[e], src, 64);
#pragma unroll
                for (int a = 0; a < 3; ++a) rk[a] += (q > p[a]);
            }
        }
    }
#pragma unroll
    for (int e = 0; e < 3; ++e) {
        if (e < S && rk[e] < 64) {
            if (p[e] >= 8192u) {                            // real entry
                ext_i[wave][rk[e]] = (unsigned short)(8191 - (p[e] & 0x1fffu));
                ext_v[wave][rk[e]] = __uint_as_float((p[e] >> 13) << 16);
            } else {                                        // filler: unique sentinel
                ext_i[wave][rk[e]] = (unsigned short)(0x2000 + rk[e]);
                ext_v[wave][rk[e]] = 0.0f;
            }
        }
    }
    // all 64 slots written by this wave; same-wave LDS ops are ordered

    // ---- exact serial-fmaf rescore of the boundary window (j = lane) ----
    const float v32 = ext_v[wave][TOPK - 1];                // approx 32nd value
    const float va  = ext_v[wave][lane];
    const int   h   = ext_i[wave][lane];
    float v = va;
    if (h < H_LAT && fabsf(va - v32) <= DELTA) {
        const float* xr  = x + (size_t)r * D_IN;
        const float* wr_ = W_enc + (size_t)h * D_IN;
        float s = 0.0f;
        for (int kk = 0; kk < D_IN / 4; ++kk) {             // serial fmaf == np oracle
            const float4 xv = ((const float4*)xr)[kk];
            const float4 dv = ((const float4*)b_dec)[kk];
            const float4 wv = ((const float4*)wr_)[kk];
            s = fmaf(xv.x - dv.x, wv.x, s);
            s = fmaf(xv.y - dv.y, wv.y, s);
            s = fmaf(xv.z - dv.z, wv.z, s);
            s = fmaf(xv.w - dv.w, wv.w, s);
        }
        v = fmaxf(s + b_enc[h], 0.0f);
    }

    // ---- final rank -> top-32 -> bf16 decoder ----
    int rank = 0;
    for (int s = 0; s < 64; ++s) {
        const int src = (lane + s) & 63;
        const float wv = __shfl(v, src, 64);
        const int   wh = __shfl(h, src, 64);
        rank += (wv > v) || (wv == v && wh < h);            // val desc, idx asc; keys unique
    }
    if (rank < TOPK) { ext_v[wave][rank] = v; ext_i[wave][rank] = (unsigned short)h; }

    const float4 bd4 = *(const float4*)&b_dec[lane * 4];
    float4 o = bd4;                                         // wave-in-order: writes visible below
#pragma unroll 8
    for (int k = 0; k < TOPK; ++k) {
        const float vv = ext_v[wave][k];                    // LDS broadcast
        const int   hh = ext_i[wave][k];
        if (hh < H_LAT) {                                   // wave-uniform (guards sentinel)
            const ushort4 w = *(const ushort4*)&Wdbf[(size_t)hh * D_IN + lane * 4];
            o.x = fmaf(vv, bf2f(w.x), o.x); o.y = fmaf(vv, bf2f(w.y), o.y);
            o.z = fmaf(vv, bf2f(w.z), o.z); o.w = fmaf(vv, bf2f(w.w), o.w);
        }
    }
    *(float4*)&out[(size_t)r * D_IN + lane * 4] = o;
}

extern "C" void kernel_launch(void* const* d_in, const int* in_sizes, int n_in,
                              void* d_out, int out_size, void* d_ws, size_t ws_size,
                              hipStream_t stream) {
    const float* x     = (const float*)d_in[0];
    const float* W_enc = (const float*)d_in[1];
    const float* b_enc = (const float*)d_in[2];
    const float* W_dec = (const float*)d_in[3];
    const float* b_dec = (const float*)d_in[4];
    float* out = (float*)d_out;

    const size_t wel = (size_t)H_LAT * D_IN;                    // 2M elements
    float* s2w = (float*)d_ws;                                  // 1 float @ offset 0
    unsigned short* Wbf  = (unsigned short*)((char*)d_ws + 256); // 4 MB bf16 W_enc (swizzled)
    unsigned short* Wdbf = Wbf + wel;                            // 4 MB bf16 W_dec (linear)
    unsigned* pool_g = (unsigned*)(Wdbf + wel);                  // 18.9 MB candidate pools
    int* cnt_g = (int*)(pool_g + (size_t)B_TOK * CAP);           // 128 KB counts

    hipMemsetAsync(d_ws, 0, 256, stream);                       // zero s2w (ws is poisoned)
    conv_kernel<<<dim3(1024), dim3(256), 0, stream>>>(W_enc, Wbf, s2w, W_dec, Wdbf);
    sae_main<<<dim3(B_TOK / MT), dim3(512), 0, stream>>>(x, b_enc, b_dec,
                                                         Wbf, s2w, pool_g, cnt_g);
    sae_select<<<dim3(B_TOK / 8), dim3(512), 0, stream>>>(x, W_enc, b_enc, b_dec,
                                                          out, Wdbf, pool_g, cnt_g);
}

// Round 10
// 542.227 us; speedup vs baseline: 1.0019x; 1.0019x over previous
//
#include <hip/hip_runtime.h>

#define B_TOK 32768
#define D_IN  256
#define H_LAT 8192
#define TOPK  32
#define MT    64          // rows per block
#define NT    128         // h-cols per chunk
#define NCH   (H_LAT / NT)
#define CAP   144         // candidate pool per row (thr=2.3sigma -> lambda~90)
#define DELTA 0.016f      // exact-rescore window; ~8 sigma of bf16-GEMM+pack err

typedef __attribute__((ext_vector_type(4))) float f32x4;
typedef __attribute__((ext_vector_type(8))) short bf16x8;

__device__ __forceinline__ unsigned short f2bf(float f) {   // RNE fp32->bf16
    unsigned u = __float_as_uint(f);
    return (unsigned short)((u + 0x7fffu + ((u >> 16) & 1u)) >> 16);
}
__device__ __forceinline__ float bf2f(unsigned short u) {
    return __uint_as_float((unsigned)u << 16);
}

// Kernel A: fused single pass: W_enc fp32 -> bf16 SWIZZLED (+ sum W^2) and
// W_dec fp32 -> bf16 linear. Same index space -> one loop, 2x loads in flight.
__global__ __launch_bounds__(256)
void conv_kernel(const float* __restrict__ W, unsigned short* __restrict__ Wbf,
                 float* __restrict__ s2w, const float* __restrict__ Wd,
                 unsigned short* __restrict__ Wdbf) {
    const int total4 = (H_LAT * D_IN) / 4;
    float acc = 0.0f;
    for (int j = blockIdx.x * blockDim.x + threadIdx.x; j < total4;
         j += gridDim.x * blockDim.x) {
        const int e4   = j & 1;                 // which half of the 8-elem frag
        const int lane = (j >> 1) & 63;
        const int c8   = (j >> 7) & 7;
        const int ct16 = j >> 10;               // 16-col tile, 0..511
        const int h = ct16 * 16 + (lane & 15);
        const int k = c8 * 32 + (lane >> 4) * 8 + e4 * 4;
        const float4 v = *(const float4*)(W + (size_t)h * D_IN + k);
        const float4 d = ((const float4*)Wd)[j];
        acc += v.x * v.x + v.y * v.y + v.z * v.z + v.w * v.w;
        ushort4 o, od;
        o.x  = f2bf(v.x); o.y  = f2bf(v.y); o.z  = f2bf(v.z); o.w  = f2bf(v.w);
        od.x = f2bf(d.x); od.y = f2bf(d.y); od.z = f2bf(d.z); od.w = f2bf(d.w);
        ((ushort4*)Wbf)[j]  = o;                // coalesced writes
        ((ushort4*)Wdbf)[j] = od;
    }
#pragma unroll
    for (int off = 32; off > 0; off >>= 1) acc += __shfl_down(acc, off, 64);
    if ((threadIdx.x & 63) == 0) atomicAdd(s2w, acc);
}

// Kernel B: GEMM + filter only (R9 verbatim: 4-chunk groups, fragment-order A,
// pool dumped coalesced to global).
__global__ __launch_bounds__(512, 4)
void sae_main(const float* __restrict__ x, const float* __restrict__ b_enc,
              const float* __restrict__ b_dec,
              const unsigned short* __restrict__ Wbf, const float* __restrict__ s2w,
              unsigned* __restrict__ pool_g, int* __restrict__ cnt_g) {
    // smem: [0, 32768)     A_frag[32][512] ushort
    //       [32768, 69632) pool[64][144]
    __shared__ __align__(16) char smem[32768 + MT * CAP * 4];
    __shared__ int   cnt[MT];
    __shared__ float thr[MT];

    unsigned short* A = (unsigned short*)smem;
    auto pool = reinterpret_cast<unsigned (*)[CAP]>(smem + 32768);

    const int tid  = threadIdx.x;
    const int row0 = blockIdx.x * MT;
    const int wave = tid >> 6, lane = tid & 63;
    const int l15 = lane & 15, quad = lane >> 4;

    if (tid < MT) { cnt[tid] = 0; thr[tid] = 0.0f; }
    __syncthreads();

    // ---- Phase 0: stage (x - b_dec) -> bf16 LDS in FRAGMENT order ----
    {
        const int r = tid >> 3, q = tid & 7;                // 8 threads/row, 32 k each
        const float* xr = x + (size_t)(row0 + r) * D_IN + q * 32;
        const float* bd = b_dec + q * 32;
        unsigned short* dst = A + ((r >> 4) * 8 + q) * 512 + (r & 15) * 8;
        float s2 = 0.0f;
#pragma unroll
        for (int j = 0; j < 4; ++j) {                       // j = quad-of-k
            const float4 a = ((const float4*)xr)[2 * j];
            const float4 b = ((const float4*)xr)[2 * j + 1];
            const float4 da = ((const float4*)bd)[2 * j];
            const float4 db = ((const float4*)bd)[2 * j + 1];
            float v[8] = {a.x - da.x, a.y - da.y, a.z - da.z, a.w - da.w,
                          b.x - db.x, b.y - db.y, b.z - db.z, b.w - db.w};
            ushort4 p0, p1;
            p0.x = f2bf(v[0]); p0.y = f2bf(v[1]); p0.z = f2bf(v[2]); p0.w = f2bf(v[3]);
            p1.x = f2bf(v[4]); p1.y = f2bf(v[5]); p1.z = f2bf(v[6]); p1.w = f2bf(v[7]);
#pragma unroll
            for (int e = 0; e < 8; ++e) s2 += v[e] * v[e];
            *(ushort4*)(dst + j * 128)     = p0;
            *(ushort4*)(dst + j * 128 + 4) = p1;
        }
        atomicAdd(&thr[r], s2);
    }
    __syncthreads();
    if (tid < MT) {
        const float s2wm = s2w[0] * (1.0f / ((float)H_LAT * (float)D_IN));
        thr[tid] = 2.3f * sqrtf(s2wm * thr[tid]);
    }
    __syncthreads();

    float thrv[4][4];
#pragma unroll
    for (int mt = 0; mt < 4; ++mt)
#pragma unroll
        for (int qi = 0; qi < 4; ++qi) thrv[mt][qi] = thr[mt * 16 + quad * 4 + qi];

    // ---- Phase 1: MFMA K-loop over 4-chunk groups; wave owns 16-col strip ----
    const unsigned short* bp = Wbf + (size_t)(wave * 8) * 512 + lane * 8;
    const unsigned short* ap = A + lane * 8;                // conflict-free A base
    const float* bep = b_enc + wave * 16 + l15;
    int col0 = wave * 16 + l15;

    int pos[4][4];
    auto collect = [&](const f32x4 (&ac)[4], int cbase) {
        const unsigned colk = (unsigned)(8191 - cbase);
#pragma unroll
        for (int mt = 0; mt < 4; ++mt)
#pragma unroll
            for (int qi = 0; qi < 4; ++qi) {
                pos[mt][qi] = -1;
                if (ac[mt][qi] > thrv[mt][qi])
                    pos[mt][qi] = atomicAdd(&cnt[mt * 16 + quad * 4 + qi], 1);
            }
#pragma unroll
        for (int mt = 0; mt < 4; ++mt)
#pragma unroll
            for (int qi = 0; qi < 4; ++qi) {
                if ((unsigned)pos[mt][qi] < CAP)
                    pool[mt * 16 + quad * 4 + qi][pos[mt][qi]] =
                        ((unsigned)f2bf(ac[mt][qi]) << 13) | colk;
            }
    };

    for (int g = 0; g < NCH; g += 4) {
        const float bv0 = bep[0],      bv1 = bep[NT];
        const float bv2 = bep[2 * NT], bv3 = bep[3 * NT];

        f32x4 acc0[4], acc1[4], acc2[4], acc3[4];
#pragma unroll
        for (int mt = 0; mt < 4; ++mt) {
            acc0[mt] = {bv0, bv0, bv0, bv0};                // C-in = bias
            acc1[mt] = {bv1, bv1, bv1, bv1};
            acc2[mt] = {bv2, bv2, bv2, bv2};
            acc3[mt] = {bv3, bv3, bv3, bv3};
        }

#pragma unroll
        for (int c8 = 0; c8 < 8; ++c8) {
            const bf16x8 a0 = *(const bf16x8*)(ap + (0 * 8 + c8) * 512);
            const bf16x8 a1 = *(const bf16x8*)(ap + (1 * 8 + c8) * 512);
            const bf16x8 a2 = *(const bf16x8*)(ap + (2 * 8 + c8) * 512);
            const bf16x8 a3 = *(const bf16x8*)(ap + (3 * 8 + c8) * 512);
            const bf16x8 w0 = *(const bf16x8*)(bp + c8 * 512);
            const bf16x8 w1 = *(const bf16x8*)(bp + 32768 + c8 * 512);
            const bf16x8 w2 = *(const bf16x8*)(bp + 65536 + c8 * 512);
            const bf16x8 w3 = *(const bf16x8*)(bp + 98304 + c8 * 512);
            acc0[0] = __builtin_amdgcn_mfma_f32_16x16x32_bf16(a0, w0, acc0[0], 0, 0, 0);
            acc0[1] = __builtin_amdgcn_mfma_f32_16x16x32_bf16(a1, w0, acc0[1], 0, 0, 0);
            acc0[2] = __builtin_amdgcn_mfma_f32_16x16x32_bf16(a2, w0, acc0[2], 0, 0, 0);
            acc0[3] = __builtin_amdgcn_mfma_f32_16x16x32_bf16(a3, w0, acc0[3], 0, 0, 0);
            acc1[0] = __builtin_amdgcn_mfma_f32_16x16x32_bf16(a0, w1, acc1[0], 0, 0, 0);
            acc1[1] = __builtin_amdgcn_mfma_f32_16x16x32_bf16(a1, w1, acc1[1], 0, 0, 0);
            acc1[2] = __builtin_amdgcn_mfma_f32_16x16x32_bf16(a2, w1, acc1[2], 0, 0, 0);
            acc1[3] = __builtin_amdgcn_mfma_f32_16x16x32_bf16(a3, w1, acc1[3], 0, 0, 0);
            acc2[0] = __builtin_amdgcn_mfma_f32_16x16x32_bf16(a0, w2, acc2[0], 0, 0, 0);
            acc2[1] = __builtin_amdgcn_mfma_f32_16x16x32_bf16(a1, w2, acc2[1], 0, 0, 0);
            acc2[2] = __builtin_amdgcn_mfma_f32_16x16x32_bf16(a2, w2, acc2[2], 0, 0, 0);
            acc2[3] = __builtin_amdgcn_mfma_f32_16x16x32_bf16(a3, w2, acc2[3], 0, 0, 0);
            acc3[0] = __builtin_amdgcn_mfma_f32_16x16x32_bf16(a0, w3, acc3[0], 0, 0, 0);
            acc3[1] = __builtin_amdgcn_mfma_f32_16x16x32_bf16(a1, w3, acc3[1], 0, 0, 0);
            acc3[2] = __builtin_amdgcn_mfma_f32_16x16x32_bf16(a2, w3, acc3[2], 0, 0, 0);
            acc3[3] = __builtin_amdgcn_mfma_f32_16x16x32_bf16(a3, w3, acc3[3], 0, 0, 0);
        }

        collect(acc0, col0);
        collect(acc1, col0 + NT);
        collect(acc2, col0 + 2 * NT);
        collect(acc3, col0 + 3 * NT);

        bp  += 4 * 32768;                                   // 4 chunks (8 ct16 each)
        bep += 4 * NT;
        col0 += 4 * NT;
    }
    __syncthreads();    // pools complete

    // ---- Dump pool + counts coalesced to global for the select kernel ----
    {
        unsigned* pg = pool_g + (size_t)row0 * CAP;
        const unsigned* ps = (const unsigned*)pool;
        for (int i = tid; i < MT * CAP; i += 512) pg[i] = ps[i];
        if (tid < MT) cnt_g[row0 + tid] = cnt[tid];
    }
}

// Kernel C: select + decode, ONE WAVE PER ROW, no barriers. Latency-bound ->
// 8 waves/EU (32 waves/CU) via __launch_bounds__(512, 8); tiny LDS (3 KB).
__global__ __launch_bounds__(512, 8)
void sae_select(const float* __restrict__ x, const float* __restrict__ W_enc,
                const float* __restrict__ b_enc, const float* __restrict__ b_dec,
                float* __restrict__ out, const unsigned short* __restrict__ Wdbf,
                const unsigned* __restrict__ pool_g, const int* __restrict__ cnt_g) {
    __shared__ unsigned short ext_i[8][64];
    __shared__ float          ext_v[8][64];

    const int tid = threadIdx.x, wave = tid >> 6, lane = tid & 63;
    const int r = blockIdx.x * 8 + wave;                    // global row
    const unsigned* pr = pool_g + (size_t)r * CAP;
    const int n = min(cnt_g[r], CAP);

    // ---- rank-count on packed keys -> top-64 (idx + approx val) ----
    unsigned p[3]; int rk[3];
    const int S = (n <= 128) ? 2 : 3;                       // wave-uniform
#pragma unroll
    for (int e = 0; e < 3; ++e) {
        const int c = e * 64 + lane;
        p[e] = (c < n) ? pr[c] : (unsigned)(c + 1);         // unique tiny sentinels
        rk[e] = 0;
    }
    if (S == 2) {
        for (int s = 0; s < 64; ++s) {
            const int src = (lane + s) & 63;
            const unsigned q0 = (unsigned)__shfl((int)p[0], src, 64);
            const unsigned q1 = (unsigned)__shfl((int)p[1], src, 64);
            rk[0] += (q0 > p[0]) + (q1 > p[0]);
            rk[1] += (q0 > p[1]) + (q1 > p[1]);
        }
    } else {
        for (int s = 0; s < 64; ++s) {
            const int src = (lane + s) & 63;
#pragma unroll
            for (int e = 0; e < 3; ++e) {
                const unsigned q = (unsigned)__shfl((int)p[e], src, 64);
#pragma unroll
                for (int a = 0; a < 3; ++a) rk[a] += (q > p[a]);
            }
        }
    }
#pragma unroll
    for (int e = 0; e < 3; ++e) {
        if (e < S && rk[e] < 64) {
            if (p[e] >= 8192u) {                            // real entry
                ext_i[wave][rk[e]] = (unsigned short)(8191 - (p[e] & 0x1fffu));
                ext_v[wave][rk[e]] = __uint_as_float((p[e] >> 13) << 16);
            } else {                                        // filler: unique sentinel
                ext_i[wave][rk[e]] = (unsigned short)(0x2000 + rk[e]);
                ext_v[wave][rk[e]] = 0.0f;
            }
        }
    }
    // all 64 slots written by this wave; same-wave LDS ops are ordered

    // ---- exact serial-fmaf rescore of the boundary window (j = lane) ----
    const float v32 = ext_v[wave][TOPK - 1];                // approx 32nd value
    const float va  = ext_v[wave][lane];
    const int   h   = ext_i[wave][lane];
    float v = va;
    if (h < H_LAT && fabsf(va - v32) <= DELTA) {
        const float* xr  = x + (size_t)r * D_IN;
        const float* wr_ = W_enc + (size_t)h * D_IN;
        float s = 0.0f;
        for (int kk = 0; kk < D_IN / 4; ++kk) {             // serial fmaf == np oracle
            const float4 xv = ((const float4*)xr)[kk];
            const float4 dv = ((const float4*)b_dec)[kk];
            const float4 wv = ((const float4*)wr_)[kk];
            s = fmaf(xv.x - dv.x, wv.x, s);
            s = fmaf(xv.y - dv.y, wv.y, s);
            s = fmaf(xv.z - dv.z, wv.z, s);
            s = fmaf(xv.w - dv.w, wv.w, s);
        }
        v = fmaxf(s + b_enc[h], 0.0f);
    }

    // ---- final rank -> top-32 -> bf16 decoder ----
    int rank = 0;
    for (int s = 0; s < 64; ++s) {
        const int src = (lane + s) & 63;
        const float wv = __shfl(v, src, 64);
        const int   wh = __shfl(h, src, 64);
        rank += (wv > v) || (wv == v && wh < h);            // val desc, idx asc; keys unique
    }
    if (rank < TOPK) { ext_v[wave][rank] = v; ext_i[wave][rank] = (unsigned short)h; }

    const float4 bd4 = *(const float4*)&b_dec[lane * 4];
    float4 o = bd4;                                         // wave-in-order: writes visible below
#pragma unroll 8
    for (int k = 0; k < TOPK; ++k) {
        const float vv = ext_v[wave][k];                    // LDS broadcast
        const int   hh = ext_i[wave][k];
        if (hh < H_LAT) {                                   // wave-uniform (guards sentinel)
            const ushort4 w = *(const ushort4*)&Wdbf[(size_t)hh * D_IN + lane * 4];
            o.x = fmaf(vv, bf2f(w.x), o.x); o.y = fmaf(vv, bf2f(w.y), o.y);
            o.z = fmaf(vv, bf2f(w.z), o.z); o.w = fmaf(vv, bf2f(w.w), o.w);
        }
    }
    *(float4*)&out[(size_t)r * D_IN + lane * 4] = o;
}

extern "C" void kernel_launch(void* const* d_in, const int* in_sizes, int n_in,
                              void* d_out, int out_size, void* d_ws, size_t ws_size,
                              hipStream_t stream) {
    const float* x     = (const float*)d_in[0];
    const float* W_enc = (const float*)d_in[1];
    const float* b_enc = (const float*)d_in[2];
    const float* W_dec = (const float*)d_in[3];
    const float* b_dec = (const float*)d_in[4];
    float* out = (float*)d_out;

    const size_t wel = (size_t)H_LAT * D_IN;                    // 2M elements
    float* s2w = (float*)d_ws;                                  // 1 float @ offset 0
    unsigned short* Wbf  = (unsigned short*)((char*)d_ws + 256); // 4 MB bf16 W_enc (swizzled)
    unsigned short* Wdbf = Wbf + wel;                            // 4 MB bf16 W_dec (linear)
    unsigned* pool_g = (unsigned*)(Wdbf + wel);                  // 18.9 MB candidate pools
    int* cnt_g = (int*)(pool_g + (size_t)B_TOK * CAP);           // 128 KB counts

    hipMemsetAsync(d_ws, 0, 256, stream);                       // zero s2w (ws is poisoned)
    conv_kernel<<<dim3(1024), dim3(256), 0, stream>>>(W_enc, Wbf, s2w, W_dec, Wdbf);
    sae_main<<<dim3(B_TOK / MT), dim3(512), 0, stream>>>(x, b_enc, b_dec,
                                                         Wbf, s2w, pool_g, cnt_g);
    sae_select<<<dim3(B_TOK / 8), dim3(512), 0, stream>>>(x, W_enc, b_enc, b_dec,
                                                          out, Wdbf, pool_g, cnt_g);
}